// Round 5
// baseline (136.692 us; speedup 1.0000x reference)
//
#include <hip/hip_runtime.h>

// ConvCapsuleLayer: B=2, 48x48, IN_CAPS=8, ATOMS=16, KER=3, OUT_CAPS=16, R=3.
// One 256-thread block per pixel (N=4232). Thread t=(o=t>>4, a=(t>>2)&3, c=t&3).
// Round-5: round-4 factorized algebra, plus:
//  - wreg2 (W[ic][o][c][:]) in registers -> w_s dead after init -> w_s/g_s share
//    one LDS buffer: 31.8 KB total -> 5 blocks/CU (launch_bounds(256,5)).
//  - phase A softmax spread over 144 threads (2 per k, DPP xor1 combine).

#define IN_CAPS 8
#define OUT_CAPS 16
#define KK 9
#define KKIN 72
#define BATCH 2
#define H_IN 48
#define W_IN 48
#define HO 46
#define WO 46
#define CIN 136
#define NPIX (BATCH*HO*WO)   // 4232

template<int CTRL>
__device__ __forceinline__ float dpp_f(float x) {
    return __int_as_float(
        __builtin_amdgcn_update_dpp(0, __float_as_int(x), CTRL, 0xF, 0xF, true));
}
// sum across the 16 lanes of a DPP row (the e-group): 4 pure-VALU adds
__device__ __forceinline__ float row_sum16(float x) {
    x += dpp_f<0xB1>(x);    // quad_perm xor1
    x += dpp_f<0x4E>(x);    // quad_perm xor2
    x += dpp_f<0x124>(x);   // row_ror:4
    x += dpp_f<0x128>(x);   // row_ror:8
    return x;
}

__global__ __launch_bounds__(256, 5)
void capsule_routing_kernel(const float* __restrict__ x,
                            const float* __restrict__ Wg,
                            float* __restrict__ out)
{
    __shared__ alignas(16) float pose_s[KKIN * 20];        // [k][atom]   5760 B
    __shared__ alignas(16) float pose_t[16 * 76];          // [a*4+b][k]  4864 B
    __shared__ float act_s[KKIN];                          //              288 B
    __shared__ alignas(16) float wg_s[IN_CAPS*OUT_CAPS*20];// W(init)/G   10240 B
    __shared__ alignas(16) float coup_s[OUT_CAPS * 76];    // [o][k]      4864 B
    __shared__ alignas(16) float logits_s[KKIN * 20];      // [k][o]      5760 B
    // total 31776 B -> 5 blocks/CU

    const int tid = threadIdx.x;
    const int o = tid >> 4;        // out capsule
    const int e = tid & 15;        // atom = a*4+c
    const int c = e & 3;

    const int n   = blockIdx.x;
    const int b   = n / (HO * WO);
    const int rem = n - b * (HO * WO);
    const int ho  = rem / WO;
    const int wo  = rem - ho * WO;

    // ---- stage W into first 2048 floats of wg_s (coalesced) ----
    for (int i = tid; i < IN_CAPS * OUT_CAPS * 16; i += 256) wg_s[i] = Wg[i];

    // ---- 3x3 patch: 9 px x 136 ch; pose stored in BOTH layouts ----
    for (int idx = tid; idx < KK * CIN; idx += 256) {
        int p  = idx / CIN;
        int cc = idx - p * CIN;
        int py = p / 3, px = p - py * 3;
        float val = x[(((b * H_IN + ho + py) * W_IN) + (wo + px)) * CIN + cc];
        int ic = cc / 17;
        int aa = cc - ic * 17;
        int k  = p * IN_CAPS + ic;
        if (aa == 16) {
            act_s[k] = val;
        } else {
            pose_s[k * 20 + aa] = val;
            pose_t[aa * 76 + k] = val;
        }
    }
    __syncthreads();

    // ---- W fragments in registers ----
    // wreg [ic][b] = W[ic][o][b][c]  (column c)  - phase B combine
    // wreg2[ic][j] = W[ic][o][c][j]  (row c)     - phase D part 1
    float wreg[IN_CAPS][4], wreg2[IN_CAPS][4];
    #pragma unroll
    for (int i = 0; i < IN_CAPS; ++i) {
        #pragma unroll
        for (int bb = 0; bb < 4; ++bb)
            wreg[i][bb] = wg_s[((i * OUT_CAPS + o) * 4 + bb) * 4 + c];
        const float4 wr = *reinterpret_cast<const float4*>(
            &wg_s[((i * OUT_CAPS + o) * 4 + c) * 4]);
        wreg2[i][0] = wr.x; wreg2[i][1] = wr.y; wreg2[i][2] = wr.z; wreg2[i][3] = wr.w;
    }

    // ---- r=0 coupling: softmax(0)*act = act/16 ----
    if (tid < KKIN) {
        float cv = act_s[tid] * 0.0625f;
        #pragma unroll
        for (int j = 0; j < OUT_CAPS; ++j) coup_s[j * 76 + tid] = cv;
    }
    __syncthreads();   // after this barrier wg_s is free to become G

    // phase-D dot assignment: thread (kbase, od) owns k = kbase+16j for j<5
    const int kbase = tid >> 4;          // 0..15
    const int od    = tid & 15;          // phase-D out capsule
    const int icd   = kbase & 7;         // ic of all owned k
    float lreg[5] = {0.f, 0.f, 0.f, 0.f, 0.f};

    const float4* cp = reinterpret_cast<const float4*>(&coup_s[o * 76]);
    const float4* pp = reinterpret_cast<const float4*>(&pose_t[e * 76]);

    float v = 0.f;
    #pragma unroll 1
    for (int r = 0; r < 3; ++r) {
        // ---- phase B: M[ic] = sum_p coup[8p+ic][o] * pose_t[e][8p+ic] ----
        float M[8] = {0.f,0.f,0.f,0.f,0.f,0.f,0.f,0.f};
        #pragma unroll
        for (int p = 0; p < KK; ++p) {
            const float4 c0 = cp[2*p], c1 = cp[2*p+1];
            const float4 p0 = pp[2*p], p1 = pp[2*p+1];
            M[0] = fmaf(c0.x, p0.x, M[0]);
            M[1] = fmaf(c0.y, p0.y, M[1]);
            M[2] = fmaf(c0.z, p0.z, M[2]);
            M[3] = fmaf(c0.w, p0.w, M[3]);
            M[4] = fmaf(c1.x, p1.x, M[4]);
            M[5] = fmaf(c1.y, p1.y, M[5]);
            M[6] = fmaf(c1.z, p1.z, M[6]);
            M[7] = fmaf(c1.w, p1.w, M[7]);
        }
        // combine: s = sum_ic sum_b wreg[ic][b] * M[ic] (b from quad lane)
        float s0 = 0.f, s1 = 0.f, s2 = 0.f, s3 = 0.f;
        #pragma unroll
        for (int ic = 0; ic < 8; ++ic) {
            s0 = fmaf(wreg[ic][0], dpp_f<0x00>(M[ic]), s0);
            s1 = fmaf(wreg[ic][1], dpp_f<0x55>(M[ic]), s1);
            s2 = fmaf(wreg[ic][2], dpp_f<0xAA>(M[ic]), s2);
            s3 = fmaf(wreg[ic][3], dpp_f<0xFF>(M[ic]), s3);
        }
        const float s = (s0 + s1) + (s2 + s3);

        // ---- phase C: squash ----
        const float sq = row_sum16(s * s);
        v = s * (sq / ((1.f + sq) * sqrtf(sq + 1e-7f)));

        if (r < 2) {
            // ---- phase D part 1: G[ic][o][a][b=c] = sum_c' W[ic][o][c][c']*v[o][a][c'] ----
            const float vq0 = dpp_f<0x00>(v);
            const float vq1 = dpp_f<0x55>(v);
            const float vq2 = dpp_f<0xAA>(v);
            const float vq3 = dpp_f<0xFF>(v);
            #pragma unroll
            for (int ic = 0; ic < 8; ++ic) {
                float g = wreg2[ic][0] * vq0 + wreg2[ic][1] * vq1
                        + wreg2[ic][2] * vq2 + wreg2[ic][3] * vq3;
                wg_s[(ic * OUT_CAPS + o) * 20 + e] = g;
            }
            __syncthreads();
            // ---- phase D part 2: owned dots P[k][od] = sum_{a,b} pose*G ----
            const float4* gp = reinterpret_cast<const float4*>(
                &wg_s[(icd * OUT_CAPS + od) * 20]);
            const float4 g0 = gp[0], g1 = gp[1], g2 = gp[2], g3 = gp[3];
            #pragma unroll
            for (int j = 0; j < 5; ++j) {
                const int k = kbase + 16 * j;
                if (k < KKIN) {   // wave-uniform
                    const float4* pk = reinterpret_cast<const float4*>(&pose_s[k * 20]);
                    const float4 p0 = pk[0], p1 = pk[1], p2 = pk[2], p3 = pk[3];
                    float d0 = p0.x*g0.x + p0.y*g0.y + p0.z*g0.z + p0.w*g0.w;
                    float d1 = p1.x*g1.x + p1.y*g1.y + p1.z*g1.z + p1.w*g1.w;
                    float d2 = p2.x*g2.x + p2.y*g2.y + p2.z*g2.z + p2.w*g2.w;
                    float d3 = p3.x*g3.x + p3.y*g3.y + p3.z*g3.z + p3.w*g3.w;
                    lreg[j] += (d0 + d1) + (d2 + d3);
                    logits_s[k * 20 + od] = lreg[j];
                }
            }
            __syncthreads();
            // ---- phase A: coup[k][o] = softmax_o(logits[k]) * act[k]
            //      2 threads per k (halves of the o-range), DPP xor1 combine ----
            if (tid < 2 * KKIN) {
                const int k  = tid >> 1;
                const int hf = tid & 1;
                const float4* lp = reinterpret_cast<const float4*>(
                    &logits_s[k * 20 + hf * 8]);
                const float4 l0 = lp[0], l1 = lp[1];
                float lg[8] = {l0.x,l0.y,l0.z,l0.w, l1.x,l1.y,l1.z,l1.w};
                float mx = -1e30f;
                #pragma unroll
                for (int j = 0; j < 8; ++j) mx = fmaxf(mx, lg[j]);
                mx = fmaxf(mx, dpp_f<0xB1>(mx));          // pair combine
                float sum = 0.f;
                #pragma unroll
                for (int j = 0; j < 8; ++j) { lg[j] = __expf(lg[j] - mx); sum += lg[j]; }
                sum += dpp_f<0xB1>(sum);                   // pair combine
                const float scale = act_s[k] / sum;
                #pragma unroll
                for (int j = 0; j < 8; ++j) coup_s[(hf * 8 + j) * 76 + k] = lg[j] * scale;
            }
            __syncthreads();
        }
    }

    // ---- out[n][o][e], coalesced ----
    out[n * 256 + tid] = v;
}

extern "C" void kernel_launch(void* const* d_in, const int* in_sizes, int n_in,
                              void* d_out, int out_size, void* d_ws, size_t ws_size,
                              hipStream_t stream) {
    const float* x  = (const float*)d_in[0];   // [2,48,48,136] fp32
    const float* Wt = (const float*)d_in[1];   // [8,16,4,4]    fp32
    float* outp = (float*)d_out;               // [2,46,46,16,16] fp32
    capsule_routing_kernel<<<dim3(NPIX), dim3(256), 0, stream>>>(x, Wt, outp);
}

// Round 6
// 98.486 us; speedup vs baseline: 1.3879x; 1.3879x over previous
//
#include <hip/hip_runtime.h>

// ConvCapsuleLayer: B=2, 48x48, IN_CAPS=8, ATOMS=16, KER=3, OUT_CAPS=16, R=3.
// One 256-thread block per pixel (N=4232). Thread t=(o=t>>4, a=(t>>2)&3, c=t&3).
// Round-6: round-5 structure (w_s/g_s aliased -> 31.8 KB LDS; phase A on 144
// threads) but launch_bounds(256,4): round-5's (256,5) capped VGPRs at ~96 and
// spilled wreg/wreg2 to scratch (WRITE_SIZE 4.2->147 MB, dur 52->89 us).
// With cap 128 the fragments stay resident; occupancy is LDS-limited at
// 5 blocks/CU.

#define IN_CAPS 8
#define OUT_CAPS 16
#define KK 9
#define KKIN 72
#define BATCH 2
#define H_IN 48
#define W_IN 48
#define HO 46
#define WO 46
#define CIN 136
#define NPIX (BATCH*HO*WO)   // 4232

template<int CTRL>
__device__ __forceinline__ float dpp_f(float x) {
    return __int_as_float(
        __builtin_amdgcn_update_dpp(0, __float_as_int(x), CTRL, 0xF, 0xF, true));
}
// sum across the 16 lanes of a DPP row (the e-group): 4 pure-VALU adds
__device__ __forceinline__ float row_sum16(float x) {
    x += dpp_f<0xB1>(x);    // quad_perm xor1
    x += dpp_f<0x4E>(x);    // quad_perm xor2
    x += dpp_f<0x124>(x);   // row_ror:4
    x += dpp_f<0x128>(x);   // row_ror:8
    return x;
}

__global__ __launch_bounds__(256, 4)
void capsule_routing_kernel(const float* __restrict__ x,
                            const float* __restrict__ Wg,
                            float* __restrict__ out)
{
    __shared__ alignas(16) float pose_s[KKIN * 20];        // [k][atom]   5760 B
    __shared__ alignas(16) float pose_t[16 * 76];          // [a*4+b][k]  4864 B
    __shared__ float act_s[KKIN];                          //              288 B
    __shared__ alignas(16) float wg_s[IN_CAPS*OUT_CAPS*20];// W(init)/G   10240 B
    __shared__ alignas(16) float coup_s[OUT_CAPS * 76];    // [o][k]      4864 B
    __shared__ alignas(16) float logits_s[KKIN * 20];      // [k][o]      5760 B
    // total 31776 B -> LDS allows 5 blocks/CU

    const int tid = threadIdx.x;
    const int o = tid >> 4;        // out capsule
    const int e = tid & 15;        // atom = a*4+c
    const int c = e & 3;

    const int n   = blockIdx.x;
    const int b   = n / (HO * WO);
    const int rem = n - b * (HO * WO);
    const int ho  = rem / WO;
    const int wo  = rem - ho * WO;

    // ---- stage W into first 2048 floats of wg_s (coalesced) ----
    for (int i = tid; i < IN_CAPS * OUT_CAPS * 16; i += 256) wg_s[i] = Wg[i];

    // ---- 3x3 patch: 9 px x 136 ch; pose stored in BOTH layouts ----
    for (int idx = tid; idx < KK * CIN; idx += 256) {
        int p  = idx / CIN;
        int cc = idx - p * CIN;
        int py = p / 3, px = p - py * 3;
        float val = x[(((b * H_IN + ho + py) * W_IN) + (wo + px)) * CIN + cc];
        int ic = cc / 17;
        int aa = cc - ic * 17;
        int k  = p * IN_CAPS + ic;
        if (aa == 16) {
            act_s[k] = val;
        } else {
            pose_s[k * 20 + aa] = val;
            pose_t[aa * 76 + k] = val;
        }
    }
    __syncthreads();

    // ---- W fragments in registers ----
    // wreg [ic][b] = W[ic][o][b][c]  (column c)  - phase B combine
    // wreg2[ic][j] = W[ic][o][c][j]  (row c)     - phase D part 1
    float wreg[IN_CAPS][4], wreg2[IN_CAPS][4];
    #pragma unroll
    for (int i = 0; i < IN_CAPS; ++i) {
        #pragma unroll
        for (int bb = 0; bb < 4; ++bb)
            wreg[i][bb] = wg_s[((i * OUT_CAPS + o) * 4 + bb) * 4 + c];
        const float4 wr = *reinterpret_cast<const float4*>(
            &wg_s[((i * OUT_CAPS + o) * 4 + c) * 4]);
        wreg2[i][0] = wr.x; wreg2[i][1] = wr.y; wreg2[i][2] = wr.z; wreg2[i][3] = wr.w;
    }

    // ---- r=0 coupling: softmax(0)*act = act/16 ----
    if (tid < KKIN) {
        float cv = act_s[tid] * 0.0625f;
        #pragma unroll
        for (int j = 0; j < OUT_CAPS; ++j) coup_s[j * 76 + tid] = cv;
    }
    __syncthreads();   // after this barrier wg_s is free to become G

    // phase-D dot assignment: thread (kbase, od) owns k = kbase+16j for j<5
    const int kbase = tid >> 4;          // 0..15
    const int od    = tid & 15;          // phase-D out capsule
    const int icd   = kbase & 7;         // ic of all owned k
    float lreg[5] = {0.f, 0.f, 0.f, 0.f, 0.f};

    const float4* cp = reinterpret_cast<const float4*>(&coup_s[o * 76]);
    const float4* pp = reinterpret_cast<const float4*>(&pose_t[e * 76]);

    float v = 0.f;
    #pragma unroll 1
    for (int r = 0; r < 3; ++r) {
        // ---- phase B: M[ic] = sum_p coup[8p+ic][o] * pose_t[e][8p+ic] ----
        float M[8] = {0.f,0.f,0.f,0.f,0.f,0.f,0.f,0.f};
        #pragma unroll
        for (int p = 0; p < KK; ++p) {
            const float4 c0 = cp[2*p], c1 = cp[2*p+1];
            const float4 p0 = pp[2*p], p1 = pp[2*p+1];
            M[0] = fmaf(c0.x, p0.x, M[0]);
            M[1] = fmaf(c0.y, p0.y, M[1]);
            M[2] = fmaf(c0.z, p0.z, M[2]);
            M[3] = fmaf(c0.w, p0.w, M[3]);
            M[4] = fmaf(c1.x, p1.x, M[4]);
            M[5] = fmaf(c1.y, p1.y, M[5]);
            M[6] = fmaf(c1.z, p1.z, M[6]);
            M[7] = fmaf(c1.w, p1.w, M[7]);
        }
        // combine: s = sum_ic sum_b wreg[ic][b] * M[ic] (b from quad lane)
        float s0 = 0.f, s1 = 0.f, s2 = 0.f, s3 = 0.f;
        #pragma unroll
        for (int ic = 0; ic < 8; ++ic) {
            s0 = fmaf(wreg[ic][0], dpp_f<0x00>(M[ic]), s0);
            s1 = fmaf(wreg[ic][1], dpp_f<0x55>(M[ic]), s1);
            s2 = fmaf(wreg[ic][2], dpp_f<0xAA>(M[ic]), s2);
            s3 = fmaf(wreg[ic][3], dpp_f<0xFF>(M[ic]), s3);
        }
        const float s = (s0 + s1) + (s2 + s3);

        // ---- phase C: squash ----
        const float sq = row_sum16(s * s);
        v = s * (sq / ((1.f + sq) * sqrtf(sq + 1e-7f)));

        if (r < 2) {
            // ---- phase D part 1: G[ic][o][a][b=c] = sum_c' W[ic][o][c][c']*v[o][a][c'] ----
            const float vq0 = dpp_f<0x00>(v);
            const float vq1 = dpp_f<0x55>(v);
            const float vq2 = dpp_f<0xAA>(v);
            const float vq3 = dpp_f<0xFF>(v);
            #pragma unroll
            for (int ic = 0; ic < 8; ++ic) {
                float g = wreg2[ic][0] * vq0 + wreg2[ic][1] * vq1
                        + wreg2[ic][2] * vq2 + wreg2[ic][3] * vq3;
                wg_s[(ic * OUT_CAPS + o) * 20 + e] = g;
            }
            __syncthreads();
            // ---- phase D part 2: owned dots P[k][od] = sum_{a,b} pose*G ----
            const float4* gp = reinterpret_cast<const float4*>(
                &wg_s[(icd * OUT_CAPS + od) * 20]);
            const float4 g0 = gp[0], g1 = gp[1], g2 = gp[2], g3 = gp[3];
            #pragma unroll
            for (int j = 0; j < 5; ++j) {
                const int k = kbase + 16 * j;
                if (k < KKIN) {   // wave-uniform
                    const float4* pk = reinterpret_cast<const float4*>(&pose_s[k * 20]);
                    const float4 p0 = pk[0], p1 = pk[1], p2 = pk[2], p3 = pk[3];
                    float d0 = p0.x*g0.x + p0.y*g0.y + p0.z*g0.z + p0.w*g0.w;
                    float d1 = p1.x*g1.x + p1.y*g1.y + p1.z*g1.z + p1.w*g1.w;
                    float d2 = p2.x*g2.x + p2.y*g2.y + p2.z*g2.z + p2.w*g2.w;
                    float d3 = p3.x*g3.x + p3.y*g3.y + p3.z*g3.z + p3.w*g3.w;
                    lreg[j] += (d0 + d1) + (d2 + d3);
                    logits_s[k * 20 + od] = lreg[j];
                }
            }
            __syncthreads();
            // ---- phase A: coup[k][o] = softmax_o(logits[k]) * act[k]
            //      2 threads per k (halves of the o-range), DPP xor1 combine ----
            if (tid < 2 * KKIN) {
                const int k  = tid >> 1;
                const int hf = tid & 1;
                const float4* lp = reinterpret_cast<const float4*>(
                    &logits_s[k * 20 + hf * 8]);
                const float4 l0 = lp[0], l1 = lp[1];
                float lg[8] = {l0.x,l0.y,l0.z,l0.w, l1.x,l1.y,l1.z,l1.w};
                float mx = -1e30f;
                #pragma unroll
                for (int j = 0; j < 8; ++j) mx = fmaxf(mx, lg[j]);
                mx = fmaxf(mx, dpp_f<0xB1>(mx));          // pair combine
                float sum = 0.f;
                #pragma unroll
                for (int j = 0; j < 8; ++j) { lg[j] = __expf(lg[j] - mx); sum += lg[j]; }
                sum += dpp_f<0xB1>(sum);                   // pair combine
                const float scale = act_s[k] / sum;
                #pragma unroll
                for (int j = 0; j < 8; ++j) coup_s[(hf * 8 + j) * 76 + k] = lg[j] * scale;
            }
            __syncthreads();
        }
    }

    // ---- out[n][o][e], coalesced ----
    out[n * 256 + tid] = v;
}

extern "C" void kernel_launch(void* const* d_in, const int* in_sizes, int n_in,
                              void* d_out, int out_size, void* d_ws, size_t ws_size,
                              hipStream_t stream) {
    const float* x  = (const float*)d_in[0];   // [2,48,48,136] fp32
    const float* Wt = (const float*)d_in[1];   // [8,16,4,4]    fp32
    float* outp = (float*)d_out;               // [2,46,46,16,16] fp32
    capsule_routing_kernel<<<dim3(NPIX), dim3(256), 0, stream>>>(x, Wt, outp);
}